// Round 2
// baseline (4056.775 us; speedup 1.0000x reference)
//
#include <hip/hip_runtime.h>

// LSTM: T=512, B=64, I=512, H=512, gates 4H=2048. Inputs fp32, output fp32.
// One persistent kernel, 64 blocks x 256 threads (4 waves).
// Block b owns h-columns [8b, 8b+8) -> gate columns {q*512 + 8b + j}.
// W slices in LDS pre-swizzled (bf16) into MFMA B-fragment order.
// h published per-step as a COMPACT 1 KB/producer slice: [buf][p][row][8cols],
// coherent write-through 8B stores / coherent 8B loads.
// Sync: per-(wave,producer) monotonic flag words, 64-lane coalesced poll.
// ROUND 10 CHANGE (x-proj off the critical chain):
//  Round 9 (sync redesign) was NEUTRAL -> the chain is NOT the sync
//  mechanism; it is dominated by the x-projection's load->cvt->MFMA loop,
//  which is load-latency-bound (few loads in flight at VGPR=88) and runs
//  serialized inside every step. Now:
//   - x A-fragments are double-buffered in REGISTERS: xa[16] (bf16x8, 64
//     VGPRs) holds step t's fragments; xproj consumes registers only
//     (16 x {2 ds_read_b128 + 2 MFMA} ~ 600 cy, no global loads).
//   - The raw fp32 loads for step t+1 are issued BEFORE the flag poll, so
//     their latency hides under poll + coherent h-load round trips.
//   - The fp32->bf16 convert runs between h-load issue and recurrent MFMA,
//     overlapping coherent-load latency (VALU slack is free there).

#define T_STEPS 512
#define BATCH   64
#define HID     512
#define NB      64

typedef short bf16x8 __attribute__((ext_vector_type(8)));
typedef float f32x4  __attribute__((ext_vector_type(4)));

struct U16B { unsigned long long x, y; };

__device__ __forceinline__ unsigned short f2bf(float f) {
    unsigned int u = __builtin_bit_cast(unsigned int, f);
    u += 0x7FFFu + ((u >> 16) & 1u);
    return (unsigned short)(u >> 16);
}
__device__ __forceinline__ unsigned int pack2(float lo, float hi) {
    return (unsigned int)f2bf(lo) | ((unsigned int)f2bf(hi) << 16);
}
// pack two float4 (8 consecutive fp32) into 16 B of bf16
__device__ __forceinline__ uint4 pack8(float4 f0, float4 f1) {
    uint4 r;
    r.x = pack2(f0.x, f0.y);
    r.y = pack2(f0.z, f0.w);
    r.z = pack2(f1.x, f1.y);
    r.w = pack2(f1.z, f1.w);
    return r;
}
// load 8 consecutive fp32 from p, round to bf16, pack into 16 B
__device__ __forceinline__ uint4 cvt8(const float* __restrict__ p) {
    float4 f0 = *(const float4*)p;
    float4 f1 = *(const float4*)(p + 4);
    return pack8(f0, f1);
}
// coherent write-through 16-byte store as 2x8B relaxed agent atomics
__device__ __forceinline__ void store_cg16(void* p, uint4 v) {
    unsigned long long* q = (unsigned long long*)p;
    U16B u = __builtin_bit_cast(U16B, v);
    __hip_atomic_store(q,     u.x, __ATOMIC_RELAXED, __HIP_MEMORY_SCOPE_AGENT);
    __hip_atomic_store(q + 1, u.y, __ATOMIC_RELAXED, __HIP_MEMORY_SCOPE_AGENT);
}
__device__ __forceinline__ float sigmoidf_(float x) {
    return 1.0f / (1.0f + __expf(-x));
}
__device__ __forceinline__ float tanhf_(float x) {
    x = fminf(fmaxf(x, -15.f), 15.f);
    float e = __expf(2.0f * x);
    return (e - 1.0f) / (e + 1.0f);
}

extern "C" __global__ void __launch_bounds__(256, 1)
lstm_fused(const float* __restrict__ x,
           const float* __restrict__ W_ih,
           const float* __restrict__ W_hh,
           const float* __restrict__ b_ih,
           const float* __restrict__ b_hh,
           float* __restrict__ out,
           unsigned int* __restrict__ flags,    // [4 waves][NB] monotonic t+1
           unsigned short* __restrict__ hbuf)   // [2][NB][64 rows][8 cols] bf16
{
    // [matrix 0=W_ih,1=W_hh][ntile][kk][lane] : 16B per lane = MFMA B-fragment
    __shared__ uint4 sB[2][2][16][64];
    // per-wave h transpose patches
    __shared__ __align__(16) unsigned short sH[4][16][8];   // bf16 (h publish)
    __shared__ __align__(16) float          sHf[4][16][8];  // fp32 (out stores)

    const int blk  = blockIdx.x;
    const int tid  = threadIdx.x;
    const int w    = tid >> 6;    // wave id 0..3 -> M-tile (batch rows 16w..16w+15)
    const int lane = tid & 63;
    const int l15  = lane & 15;
    const int quad = lane >> 4;
    const int hc0  = blk * 8;     // first owned h-column

    // ---- one-time: stage W slices into LDS in B-fragment order (fp32 -> bf16) ----
    for (int u = tid; u < 2 * 16 * 64; u += 256) {
        int nt   = u >> 10;
        int kk   = (u >> 6) & 15;
        int ln   = u & 63;
        int c    = (ln & 15) + (nt << 4);                 // local gate col 0..31
        int grow = ((c >> 3) << 9) + hc0 + (c & 7);       // global W row (gate*512 + hcol)
        int k0   = kk * 32 + ((ln >> 4) << 3);
        sB[0][nt][kk][ln] = cvt8(W_ih + grow * 512 + k0);
        sB[1][nt][kk][ln] = cvt8(W_hh + grow * 512 + k0);
    }

    // per-lane biases for its two gate columns (fp32)
    float bias0, bias1;
    {
        int c0 = l15,      g0 = ((c0 >> 3) << 9) + hc0 + (c0 & 7);
        int c1 = l15 + 16, g1 = ((c1 >> 3) << 9) + hc0 + (c1 & 7);
        bias0 = b_ih[g0] + b_hh[g0];
        bias1 = b_ih[g1] + b_hh[g1];
    }
    __syncthreads();   // sB ready; after this the 4 waves never re-sync

    float cst[4] = {0.f, 0.f, 0.f, 0.f};     // c-state: 4 rows of owned column (lanes l15<8)
    const int aoff = (((w << 4) + l15) * 512) + (quad << 3);  // x A-fragment lane offset
    // consumer h-read base (row = 16w+l15, producer varies per fragment/quad)
    char* const hb_base = (char*)hbuf;
    const int   hread_off = (quad << 10) + (((w << 4) + l15) << 4);
    unsigned int* const       my_flag = flags + (w << 6) + blk;   // this wave's publish flag
    const unsigned int* const poll_p  = flags + (w << 6) + lane;  // lane p polls producer p
    long long budget = 400000LL;              // deadlock safety valve (~poll iters)

    // ---- prologue: fill xa with step-0 A-fragments (one-time stall is fine) ----
    bf16x8 xa[16];
#pragma unroll
    for (int kk = 0; kk < 16; ++kk)
        xa[kk] = __builtin_bit_cast(bf16x8, cvt8(x + aoff + kk * 32));

    for (int t = 0; t < T_STEPS; ++t) {
        // ---- early flag probe: issue BEFORE xproj so the detect RT hides ----
        unsigned int early = 0u;
        if (t > 0)
            early = __hip_atomic_load(poll_p, __ATOMIC_RELAXED,
                                      __HIP_MEMORY_SCOPE_AGENT);
        __builtin_amdgcn_sched_barrier(0);   // pin the probe issue before xproj

        f32x4 acc0 = {0.f, 0.f, 0.f, 0.f};
        f32x4 acc1 = {0.f, 0.f, 0.f, 0.f};

        // ---- x-projection: registers only (fragments preloaded last step) ----
#pragma unroll
        for (int kk = 0; kk < 16; ++kk) {
            bf16x8 b0 = __builtin_bit_cast(bf16x8, sB[0][0][kk][lane]);
            bf16x8 b1 = __builtin_bit_cast(bf16x8, sB[0][1][kk][lane]);
            acc0 = __builtin_amdgcn_mfma_f32_16x16x32_bf16(xa[kk], b0, acc0, 0, 0, 0);
            acc1 = __builtin_amdgcn_mfma_f32_16x16x32_bf16(xa[kk], b1, acc1, 0, 0, 0);
        }

        // ---- issue raw fp32 x-loads for step t+1 (latency hides under poll
        //      + coherent h-load round trips below) ----
        const int tn = (t + 1 < T_STEPS) ? (t + 1) : t;   // clamp: avoid OOB
        const float* xn = x + (size_t)tn * (BATCH * 512) + aoff;
        float4 xr[32];
#pragma unroll
        for (int kk = 0; kk < 16; ++kk) {
            xr[2 * kk]     = *(const float4*)(xn + kk * 32);
            xr[2 * kk + 1] = *(const float4*)(xn + kk * 32 + 4);
        }

        if (t > 0) {
            // ---- wait for all 64 producers' step t-1 flags ----
            const unsigned int tgt = (unsigned int)t;
            if (!__all(early >= tgt)) {
                while (budget > 0) {
                    unsigned int v = __hip_atomic_load(poll_p, __ATOMIC_RELAXED,
                                                       __HIP_MEMORY_SCOPE_AGENT);
                    if (__all(v >= tgt)) break;   // one coalesced 256B load/iter
                    --budget;
                }
            }

            // PRELOAD all h fragments: 32 independent coherent 8B loads in flight
            const char* hp = hb_base + (((t - 1) & 1) << 16) + hread_off;
            U16B ha[16];
#pragma unroll
            for (int kk = 0; kk < 16; ++kk) {
                const unsigned long long* q =
                    (const unsigned long long*)(hp + (kk << 12));
                ha[kk].x = __hip_atomic_load(q,     __ATOMIC_RELAXED,
                                             __HIP_MEMORY_SCOPE_AGENT);
                ha[kk].y = __hip_atomic_load(q + 1, __ATOMIC_RELAXED,
                                             __HIP_MEMORY_SCOPE_AGENT);
            }

            // cvt x(t+1) -> xa while the coherent h loads are in flight
            // (x data arrived during the poll; VALU here is free slack)
#pragma unroll
            for (int kk = 0; kk < 16; ++kk)
                xa[kk] = __builtin_bit_cast(bf16x8, pack8(xr[2 * kk], xr[2 * kk + 1]));

            // consume: backend pipelines vmcnt waits across the batch
#pragma unroll
            for (int kk = 0; kk < 16; ++kk) {
                bf16x8 a  = __builtin_bit_cast(bf16x8, ha[kk]);
                bf16x8 b0 = __builtin_bit_cast(bf16x8, sB[1][0][kk][lane]);
                bf16x8 b1 = __builtin_bit_cast(bf16x8, sB[1][1][kk][lane]);
                acc0 = __builtin_amdgcn_mfma_f32_16x16x32_bf16(a, b0, acc0, 0, 0, 0);
                acc1 = __builtin_amdgcn_mfma_f32_16x16x32_bf16(a, b1, acc1, 0, 0, 0);
            }
        } else {
            // t==0: no recurrent part; just convert the prefetched x
#pragma unroll
            for (int kk = 0; kk < 16; ++kk)
                xa[kk] = __builtin_bit_cast(bf16x8, pack8(xr[2 * kk], xr[2 * kk + 1]));
        }

        // ---- gates + state update ----
        // C-layout: col = lane&15, row = quad*4 + reg.
        // acc0 col c=l15      : gate i (l15<8) / f (l15>=8), h-col = hc0 + (l15&7)
        // acc1 col c=l15+16   : gate g (l15<8) / o (l15>=8)
        float gi[4], gf[4], gg[4], go[4];
#pragma unroll
        for (int r = 0; r < 4; ++r) {
            float a0 = acc0[r] + bias0;
            float a1 = acc1[r] + bias1;
            float p0 = __shfl_xor(a0, 8, 64);
            float p1 = __shfl_xor(a1, 8, 64);
            gi[r] = a0; gg[r] = a1; gf[r] = p0; go[r] = p1;
        }
        if (l15 < 8) {
#pragma unroll
            for (int r = 0; r < 4; ++r) {
                float iv = sigmoidf_(gi[r]);
                float fv = sigmoidf_(gf[r]);
                float gv = tanhf_(gg[r]);
                float ov = sigmoidf_(go[r]);
                cst[r] = fv * cst[r] + iv * gv;
                float hv = ov * tanhf_(cst[r]);
                // transpose through per-wave LDS patches (same-wave write->read)
                sH [w][(quad << 2) + r][l15] = f2bf(hv);
                sHf[w][(quad << 2) + r][l15] = hv;
            }
        }
        asm volatile("s_waitcnt lgkmcnt(0)" ::: "memory");
        // 16 lanes publish this wave's 16 rows: coalesced 16 B each (one 256B line)
        if (lane < 16) {
            uint4 v = *(const uint4*)&sH[w][lane][0];
            char* dst = hb_base + ((t & 1) << 16) + (blk << 10)
                        + (((w << 4) + lane) << 4);
            store_cg16(dst, v);
        }
        asm volatile("s_waitcnt vmcnt(0)" ::: "memory");  // h stores acked at LLC
        // flag publish: plain relaxed store, monotonic value t+1 (no RMW, no
        // same-address serialization across producers)
        if (lane == 0) {
            __hip_atomic_store(my_flag, (unsigned int)(t + 1),
                               __ATOMIC_RELAXED, __HIP_MEMORY_SCOPE_AGENT);
        }

        // ---- fp32 output stores: coalesced, OFF the critical chain ----
        if (lane < 32) {
            int row  = lane & 15;        // row within wave's M-tile
            int half = lane >> 4;        // which 16 B of the 32 B row-slice
            uint4 v = *(const uint4*)&sHf[w][row][half << 2];
            float* op = out + (size_t)t * (BATCH * HID)
                        + (size_t)((w << 4) + row) * HID + hc0 + (half << 2);
            *(uint4*)op = v;
        }
    }
}

extern "C" void kernel_launch(void* const* d_in, const int* in_sizes, int n_in,
                              void* d_out, int out_size, void* d_ws, size_t ws_size,
                              hipStream_t stream) {
    const float* x    = (const float*)d_in[0];
    const float* W_ih = (const float*)d_in[1];
    const float* W_hh = (const float*)d_in[2];
    const float* b_ih = (const float*)d_in[3];
    const float* b_hh = (const float*)d_in[4];
    float* out = (float*)d_out;

    unsigned int*   flags = (unsigned int*)d_ws;
    const size_t    flag_bytes = 4 * NB * sizeof(unsigned int);   // 1 KB
    unsigned short* hbuf = (unsigned short*)((char*)d_ws + 1024); // 128 KB

    // flags re-zeroed every call (ws is re-poisoned to 0xAA by the harness;
    // 0xAAAAAAAA would read as "already published" — must clear)
    (void)hipMemsetAsync(flags, 0, flag_bytes, stream);

    hipLaunchKernelGGL(lstm_fused, dim3(NB), dim3(256), 0, stream,
                       x, W_ih, W_hh, b_ih, b_hh, out, flags, hbuf);
}

// Round 3
// 4037.262 us; speedup vs baseline: 1.0048x; 1.0048x over previous
//
#include <hip/hip_runtime.h>

// LSTM: T=512, B=64, I=512, H=512, gates 4H=2048. Inputs fp32, output fp32.
// One persistent kernel, 64 blocks x 256 threads (4 waves).
// Block b owns h-columns [8b, 8b+8) -> gate columns {q*512 + 8b + j}.
// W slices in LDS pre-swizzled (bf16) into MFMA B-fragment order.
// ROUND 11 CHANGE (tag-in-data rendezvous — remove coherence hops):
//  Rounds 9/10 (sync mechanism, x-proj registers) were BOTH neutral ->
//  the chain is the NUMBER of serialized agent-scope round trips
//  (publish ack -> flag -> detect -> load ~= 3.5 RTs x ~600ns), which
//  neither round reduced. Now the step tag is EMBEDDED IN THE DATA:
//  each published h value is a 32-bit word  (bf16(h) << 16) | (t+1).
//  An 8B agent-scope atomic store carries 2 such words indivisibly, so a
//  consumer load that observes the tag has valid data by atomicity.
//   - producer: gates -> LDS transpose -> 8B tagged stores, NO vmcnt ack,
//     NO flag store (fire-and-forget).
//   - consumer: retry-load the 64x8B fragments until all per-lane tags
//     == t (detect IS the load), then repack top halves -> bf16 MFMA A.
//  Chain: ~1.5 RT/step instead of ~3.5. Numerics unchanged (MFMA consumes
//  exactly the bf16 top halves that were published before).

#define T_STEPS 512
#define BATCH   64
#define HID     512
#define NB      64

typedef short bf16x8 __attribute__((ext_vector_type(8)));
typedef float f32x4  __attribute__((ext_vector_type(4)));

struct U16B { unsigned long long x, y; };

__device__ __forceinline__ unsigned short f2bf(float f) {
    unsigned int u = __builtin_bit_cast(unsigned int, f);
    u += 0x7FFFu + ((u >> 16) & 1u);
    return (unsigned short)(u >> 16);
}
__device__ __forceinline__ unsigned int pack2(float lo, float hi) {
    return (unsigned int)f2bf(lo) | ((unsigned int)f2bf(hi) << 16);
}
// load 8 consecutive fp32 from p, round to bf16, pack into 16 B
__device__ __forceinline__ uint4 cvt8(const float* __restrict__ p) {
    float4 f0 = *(const float4*)p;
    float4 f1 = *(const float4*)(p + 4);
    uint4 r;
    r.x = pack2(f0.x, f0.y);
    r.y = pack2(f0.z, f0.w);
    r.z = pack2(f1.x, f1.y);
    r.w = pack2(f1.z, f1.w);
    return r;
}
// coherent write-through 16-byte store as 2x8B relaxed agent atomics
__device__ __forceinline__ void store_cg16(void* p, uint4 v) {
    unsigned long long* q = (unsigned long long*)p;
    U16B u = __builtin_bit_cast(U16B, v);
    __hip_atomic_store(q,     u.x, __ATOMIC_RELAXED, __HIP_MEMORY_SCOPE_AGENT);
    __hip_atomic_store(q + 1, u.y, __ATOMIC_RELAXED, __HIP_MEMORY_SCOPE_AGENT);
}
__device__ __forceinline__ float sigmoidf_(float x) {
    return 1.0f / (1.0f + __expf(-x));
}
__device__ __forceinline__ float tanhf_(float x) {
    x = fminf(fmaxf(x, -15.f), 15.f);
    float e = __expf(2.0f * x);
    return (e - 1.0f) / (e + 1.0f);
}

extern "C" __global__ void __launch_bounds__(256, 1)
lstm_fused(const float* __restrict__ x,
           const float* __restrict__ W_ih,
           const float* __restrict__ W_hh,
           const float* __restrict__ b_ih,
           const float* __restrict__ b_hh,
           float* __restrict__ out,
           unsigned int* __restrict__ hbuf)   // [2][NB][64 rows][8 cols] u32 tagged
{
    // [matrix 0=W_ih,1=W_hh][ntile][kk][lane] : 16B per lane = MFMA B-fragment
    __shared__ uint4 sB[2][2][16][64];
    // per-wave transpose patches
    __shared__ __align__(16) unsigned int sHt[4][16][8];  // tagged words (publish)
    __shared__ __align__(16) float        sHf[4][16][8];  // fp32 (out stores)

    const int blk  = blockIdx.x;
    const int tid  = threadIdx.x;
    const int w    = tid >> 6;    // wave id 0..3 -> M-tile (batch rows 16w..16w+15)
    const int lane = tid & 63;
    const int l15  = lane & 15;
    const int quad = lane >> 4;
    const int hc0  = blk * 8;     // first owned h-column

    // ---- one-time: stage W slices into LDS in B-fragment order (fp32 -> bf16) ----
    for (int u = tid; u < 2 * 16 * 64; u += 256) {
        int nt   = u >> 10;
        int kk   = (u >> 6) & 15;
        int ln   = u & 63;
        int c    = (ln & 15) + (nt << 4);                 // local gate col 0..31
        int grow = ((c >> 3) << 9) + hc0 + (c & 7);       // global W row (gate*512 + hcol)
        int k0   = kk * 32 + ((ln >> 4) << 3);
        sB[0][nt][kk][ln] = cvt8(W_ih + grow * 512 + k0);
        sB[1][nt][kk][ln] = cvt8(W_hh + grow * 512 + k0);
    }

    // per-lane biases for its two gate columns (fp32)
    float bias0, bias1;
    {
        int c0 = l15,      g0 = ((c0 >> 3) << 9) + hc0 + (c0 & 7);
        int c1 = l15 + 16, g1 = ((c1 >> 3) << 9) + hc0 + (c1 & 7);
        bias0 = b_ih[g0] + b_hh[g0];
        bias1 = b_ih[g1] + b_hh[g1];
    }
    __syncthreads();   // sB ready; the 4 waves never re-sync after this

    float cst[4] = {0.f, 0.f, 0.f, 0.f};     // c-state: 4 rows of owned column (lanes l15<8)
    const int aoff = (((w << 4) + l15) * 512) + (quad << 3);  // x A-fragment lane offset
    // consumer h-read base: row = 16w+l15 (32B row slice), producer kk*4+quad
    char* const hb_base  = (char*)hbuf;
    const int   hread_off = (quad << 11) + (((w << 4) + l15) << 5);
    long long budget = 2000000LL;             // deadlock safety valve (~retry iters)

    for (int t = 0; t < T_STEPS; ++t) {
        f32x4 acc0 = {0.f, 0.f, 0.f, 0.f};
        f32x4 acc1 = {0.f, 0.f, 0.f, 0.f};

        // ---- x-projection (no cross-block dependency; hides producer skew) ----
        const float* xt = x + (size_t)t * (BATCH * 512) + aoff;
#pragma unroll
        for (int kk = 0; kk < 16; ++kk) {
            bf16x8 a  = __builtin_bit_cast(bf16x8, cvt8(xt + kk * 32));
            bf16x8 b0 = __builtin_bit_cast(bf16x8, sB[0][0][kk][lane]);
            bf16x8 b1 = __builtin_bit_cast(bf16x8, sB[0][1][kk][lane]);
            acc0 = __builtin_amdgcn_mfma_f32_16x16x32_bf16(a, b0, acc0, 0, 0, 0);
            acc1 = __builtin_amdgcn_mfma_f32_16x16x32_bf16(a, b1, acc1, 0, 0, 0);
        }

        // ---- recurrent part: retry-load tagged h until all tags == t ----
        if (t > 0) {
            const char* hp = hb_base + (((t - 1) & 1) << 17) + hread_off;
            const unsigned int tgt = (unsigned int)t;
            unsigned long long hw[64];
            for (;;) {
                // 64 independent 8B coherent loads in flight together
#pragma unroll
                for (int kk = 0; kk < 16; ++kk) {
                    const unsigned long long* q =
                        (const unsigned long long*)(hp + (kk << 13));
#pragma unroll
                    for (int j = 0; j < 4; ++j)
                        hw[kk * 4 + j] = __hip_atomic_load(q + j, __ATOMIC_RELAXED,
                                                           __HIP_MEMORY_SCOPE_AGENT);
                }
                // validate: low 16 bits of each 8B's low word carry the tag;
                // the 8B store was atomic, so one tag validates all 4 bf16
                unsigned int m = 0;
#pragma unroll
                for (int i = 0; i < 64; ++i)
                    m |= ((unsigned int)hw[i] ^ tgt) & 0xffffu;
                if (__all(m == 0)) break;
                if (--budget < 0) break;   // safety valve
            }
            // repack top halves -> bf16 A-fragments and consume
#pragma unroll
            for (int kk = 0; kk < 16; ++kk) {
                unsigned int w0 = (unsigned int)(hw[4 * kk + 0]);
                unsigned int w1 = (unsigned int)(hw[4 * kk + 0] >> 32);
                unsigned int w2 = (unsigned int)(hw[4 * kk + 1]);
                unsigned int w3 = (unsigned int)(hw[4 * kk + 1] >> 32);
                unsigned int w4 = (unsigned int)(hw[4 * kk + 2]);
                unsigned int w5 = (unsigned int)(hw[4 * kk + 2] >> 32);
                unsigned int w6 = (unsigned int)(hw[4 * kk + 3]);
                unsigned int w7 = (unsigned int)(hw[4 * kk + 3] >> 32);
                uint4 u;
                u.x = (w0 >> 16) | (w1 & 0xffff0000u);
                u.y = (w2 >> 16) | (w3 & 0xffff0000u);
                u.z = (w4 >> 16) | (w5 & 0xffff0000u);
                u.w = (w6 >> 16) | (w7 & 0xffff0000u);
                bf16x8 a  = __builtin_bit_cast(bf16x8, u);
                bf16x8 b0 = __builtin_bit_cast(bf16x8, sB[1][0][kk][lane]);
                bf16x8 b1 = __builtin_bit_cast(bf16x8, sB[1][1][kk][lane]);
                acc0 = __builtin_amdgcn_mfma_f32_16x16x32_bf16(a, b0, acc0, 0, 0, 0);
                acc1 = __builtin_amdgcn_mfma_f32_16x16x32_bf16(a, b1, acc1, 0, 0, 0);
            }
        }

        // ---- gates + state update ----
        // C-layout: col = lane&15, row = quad*4 + reg.
        // acc0 col c=l15      : gate i (l15<8) / f (l15>=8), h-col = hc0 + (l15&7)
        // acc1 col c=l15+16   : gate g (l15<8) / o (l15>=8)
        float gi[4], gf[4], gg[4], go[4];
#pragma unroll
        for (int r = 0; r < 4; ++r) {
            float a0 = acc0[r] + bias0;
            float a1 = acc1[r] + bias1;
            float p0 = __shfl_xor(a0, 8, 64);
            float p1 = __shfl_xor(a1, 8, 64);
            gi[r] = a0; gg[r] = a1; gf[r] = p0; go[r] = p1;
        }
        const unsigned int tagv = (unsigned int)(t + 1);
        if (l15 < 8) {
#pragma unroll
            for (int r = 0; r < 4; ++r) {
                float iv = sigmoidf_(gi[r]);
                float fv = sigmoidf_(gf[r]);
                float gv = tanhf_(gg[r]);
                float ov = sigmoidf_(go[r]);
                cst[r] = fv * cst[r] + iv * gv;
                float hv = ov * tanhf_(cst[r]);
                // transpose through per-wave LDS patches (same-wave write->read)
                sHt[w][(quad << 2) + r][l15] =
                    ((unsigned int)f2bf(hv) << 16) | tagv;   // tag rides with data
                sHf[w][(quad << 2) + r][l15] = hv;
            }
        }
        asm volatile("s_waitcnt lgkmcnt(0)" ::: "memory");
        // 32 lanes publish this wave's 16 rows x 32B: fire-and-forget tagged
        // 8B atomics — NO vmcnt ack, NO flag (tag-in-data makes them valid)
        if (lane < 32) {
            int row  = lane >> 1;       // row within wave's M-tile
            int half = lane & 1;        // which 16 B of the 32 B row-slice
            uint4 v = *(const uint4*)&sHt[w][row][half << 2];
            char* dst = hb_base + ((t & 1) << 17) + (blk << 11)
                        + (((w << 4) + row) << 5) + (half << 4);
            store_cg16(dst, v);
        }

        // ---- fp32 output stores: coalesced, OFF the critical chain ----
        if (lane < 32) {
            int row  = lane & 15;        // row within wave's M-tile
            int half = lane >> 4;        // which 16 B of the 32 B row-slice
            uint4 v = *(const uint4*)&sHf[w][row][half << 2];
            float* op = out + (size_t)t * (BATCH * HID)
                        + (size_t)((w << 4) + row) * HID + hc0 + (half << 2);
            *(uint4*)op = v;
        }
    }
}

extern "C" void kernel_launch(void* const* d_in, const int* in_sizes, int n_in,
                              void* d_out, int out_size, void* d_ws, size_t ws_size,
                              hipStream_t stream) {
    const float* x    = (const float*)d_in[0];
    const float* W_ih = (const float*)d_in[1];
    const float* W_hh = (const float*)d_in[2];
    const float* b_ih = (const float*)d_in[3];
    const float* b_hh = (const float*)d_in[4];
    float* out = (float*)d_out;

    // hbuf: [2][64 producers][64 rows][8 cols] u32 tagged = 256 KB
    unsigned int* hbuf = (unsigned int*)d_ws;
    // zero tags each call (tag 0 never matches any step's tgt>=1; also
    // guards against harness poison 0xAAAAAAAA which has tag 0xAAAA > 512)
    (void)hipMemsetAsync(hbuf, 0, 2 * NB * 64 * 8 * sizeof(unsigned int), stream);

    hipLaunchKernelGGL(lstm_fused, dim3(NB), dim3(256), 0, stream,
                       x, W_ih, W_hh, b_ih, b_hh, out, hbuf);
}

// Round 4
// 4024.660 us; speedup vs baseline: 1.0080x; 1.0031x over previous
//
#include <hip/hip_runtime.h>

// LSTM: T=512, B=64, I=512, H=512, gates 4H=2048. Inputs fp32, output fp32.
// Persistent kernel. 64 REAL blocks (4 waves) run the round-3 tag-in-data
// recurrence unchanged. ROUND 12 CHANGE (clock-governor experiment):
//  Rounds 9-11 (three structurally different sync schemes) were ALL exactly
//  neutral at ~7.7us/step, while cycle arithmetic predicts ~0.8us/step of
//  dependent chain at 2.4 GHz. Leading hypothesis: at 3% occupancy / 5%
//  VALU the power governor parks the chip near its floor clock (~300-500
//  MHz), inflating all latencies uniformly -> every structural change
//  neutral. TEST: launch 256 blocks; blocks 64..255 are BURNERS that run
//  dense VALU FMA chains on the idle 192 CUs until the real blocks set a
//  done counter (realtime-capped for guaranteed exit). If the governor is
//  the floor, clocks ramp and the UNCHANGED recurrence shrinks by the
//  clock ratio; if neutral, the clock is exonerated.

#define T_STEPS 512
#define BATCH   64
#define HID     512
#define NB      64          // real blocks
#define NB_TOT  256         // real + burner blocks
#define HBUF_BYTES (1 << 18)  // 256 KB tagged h buffer

typedef short bf16x8 __attribute__((ext_vector_type(8)));
typedef float f32x4  __attribute__((ext_vector_type(4)));

struct U16B { unsigned long long x, y; };

__device__ __forceinline__ unsigned short f2bf(float f) {
    unsigned int u = __builtin_bit_cast(unsigned int, f);
    u += 0x7FFFu + ((u >> 16) & 1u);
    return (unsigned short)(u >> 16);
}
__device__ __forceinline__ unsigned int pack2(float lo, float hi) {
    return (unsigned int)f2bf(lo) | ((unsigned int)f2bf(hi) << 16);
}
// load 8 consecutive fp32 from p, round to bf16, pack into 16 B
__device__ __forceinline__ uint4 cvt8(const float* __restrict__ p) {
    float4 f0 = *(const float4*)p;
    float4 f1 = *(const float4*)(p + 4);
    uint4 r;
    r.x = pack2(f0.x, f0.y);
    r.y = pack2(f0.z, f0.w);
    r.z = pack2(f1.x, f1.y);
    r.w = pack2(f1.z, f1.w);
    return r;
}
// coherent write-through 16-byte store as 2x8B relaxed agent atomics
__device__ __forceinline__ void store_cg16(void* p, uint4 v) {
    unsigned long long* q = (unsigned long long*)p;
    U16B u = __builtin_bit_cast(U16B, v);
    __hip_atomic_store(q,     u.x, __ATOMIC_RELAXED, __HIP_MEMORY_SCOPE_AGENT);
    __hip_atomic_store(q + 1, u.y, __ATOMIC_RELAXED, __HIP_MEMORY_SCOPE_AGENT);
}
__device__ __forceinline__ float sigmoidf_(float x) {
    return 1.0f / (1.0f + __expf(-x));
}
__device__ __forceinline__ float tanhf_(float x) {
    x = fminf(fmaxf(x, -15.f), 15.f);
    float e = __expf(2.0f * x);
    return (e - 1.0f) / (e + 1.0f);
}

extern "C" __global__ void __launch_bounds__(256, 1)
lstm_fused(const float* __restrict__ x,
           const float* __restrict__ W_ih,
           const float* __restrict__ W_hh,
           const float* __restrict__ b_ih,
           const float* __restrict__ b_hh,
           float* __restrict__ out,
           unsigned int* __restrict__ hbuf,   // [2][NB][64 rows][8 cols] u32 tagged
           unsigned int* __restrict__ done)   // completion counter (real blocks)
{
    const int blk  = blockIdx.x;
    const int tid  = threadIdx.x;

    // ================= BURNER BLOCKS: keep the governor awake ============
    if (blk >= NB) {
        const unsigned long long t0 = __builtin_amdgcn_s_memrealtime();
        float a0 = 1.0f + tid, a1 = 2.0f, a2 = 3.0f, a3 = 4.0f;
        float a4 = 5.0f, a5 = 6.0f, a6 = 7.0f, a7 = 8.0f;
        for (;;) {
#pragma unroll 16
            for (int i = 0; i < 512; ++i) {
                a0 = __builtin_fmaf(a0, 1.0000001f, 1.0e-7f);
                a1 = __builtin_fmaf(a1, 1.0000001f, 1.0e-7f);
                a2 = __builtin_fmaf(a2, 1.0000001f, 1.0e-7f);
                a3 = __builtin_fmaf(a3, 1.0000001f, 1.0e-7f);
                a4 = __builtin_fmaf(a4, 1.0000001f, 1.0e-7f);
                a5 = __builtin_fmaf(a5, 1.0000001f, 1.0e-7f);
                a6 = __builtin_fmaf(a6, 1.0000001f, 1.0e-7f);
                a7 = __builtin_fmaf(a7, 1.0000001f, 1.0e-7f);
            }
            asm volatile("" : "+v"(a0), "+v"(a1), "+v"(a2), "+v"(a3),
                              "+v"(a4), "+v"(a5), "+v"(a6), "+v"(a7));
            unsigned int d = __hip_atomic_load(done, __ATOMIC_RELAXED,
                                               __HIP_MEMORY_SCOPE_AGENT);
            if (d >= (unsigned int)NB) break;
            // hard realtime cap (~20ms at 100MHz ref clk): guaranteed exit
            if (__builtin_amdgcn_s_memrealtime() - t0 > 2000000ULL) break;
        }
        return;
    }

    // ================= REAL BLOCKS: round-3 code, unchanged ==============
    // [matrix 0=W_ih,1=W_hh][ntile][kk][lane] : 16B per lane = MFMA B-fragment
    __shared__ uint4 sB[2][2][16][64];
    // per-wave transpose patches
    __shared__ __align__(16) unsigned int sHt[4][16][8];  // tagged words (publish)
    __shared__ __align__(16) float        sHf[4][16][8];  // fp32 (out stores)

    const int w    = tid >> 6;    // wave id 0..3 -> M-tile (batch rows 16w..16w+15)
    const int lane = tid & 63;
    const int l15  = lane & 15;
    const int quad = lane >> 4;
    const int hc0  = blk * 8;     // first owned h-column

    // ---- one-time: stage W slices into LDS in B-fragment order (fp32 -> bf16) ----
    for (int u = tid; u < 2 * 16 * 64; u += 256) {
        int nt   = u >> 10;
        int kk   = (u >> 6) & 15;
        int ln   = u & 63;
        int c    = (ln & 15) + (nt << 4);                 // local gate col 0..31
        int grow = ((c >> 3) << 9) + hc0 + (c & 7);       // global W row (gate*512 + hcol)
        int k0   = kk * 32 + ((ln >> 4) << 3);
        sB[0][nt][kk][ln] = cvt8(W_ih + grow * 512 + k0);
        sB[1][nt][kk][ln] = cvt8(W_hh + grow * 512 + k0);
    }

    // per-lane biases for its two gate columns (fp32)
    float bias0, bias1;
    {
        int c0 = l15,      g0 = ((c0 >> 3) << 9) + hc0 + (c0 & 7);
        int c1 = l15 + 16, g1 = ((c1 >> 3) << 9) + hc0 + (c1 & 7);
        bias0 = b_ih[g0] + b_hh[g0];
        bias1 = b_ih[g1] + b_hh[g1];
    }
    __syncthreads();   // sB ready; the 4 waves never re-sync after this

    float cst[4] = {0.f, 0.f, 0.f, 0.f};     // c-state: 4 rows of owned column (lanes l15<8)
    const int aoff = (((w << 4) + l15) * 512) + (quad << 3);  // x A-fragment lane offset
    // consumer h-read base: row = 16w+l15 (32B row slice), producer kk*4+quad
    char* const hb_base  = (char*)hbuf;
    const int   hread_off = (quad << 11) + (((w << 4) + l15) << 5);
    long long budget = 2000000LL;             // deadlock safety valve (~retry iters)

    for (int t = 0; t < T_STEPS; ++t) {
        f32x4 acc0 = {0.f, 0.f, 0.f, 0.f};
        f32x4 acc1 = {0.f, 0.f, 0.f, 0.f};

        // ---- x-projection (no cross-block dependency; hides producer skew) ----
        const float* xt = x + (size_t)t * (BATCH * 512) + aoff;
#pragma unroll
        for (int kk = 0; kk < 16; ++kk) {
            bf16x8 a  = __builtin_bit_cast(bf16x8, cvt8(xt + kk * 32));
            bf16x8 b0 = __builtin_bit_cast(bf16x8, sB[0][0][kk][lane]);
            bf16x8 b1 = __builtin_bit_cast(bf16x8, sB[0][1][kk][lane]);
            acc0 = __builtin_amdgcn_mfma_f32_16x16x32_bf16(a, b0, acc0, 0, 0, 0);
            acc1 = __builtin_amdgcn_mfma_f32_16x16x32_bf16(a, b1, acc1, 0, 0, 0);
        }

        // ---- recurrent part: retry-load tagged h until all tags == t ----
        if (t > 0) {
            const char* hp = hb_base + (((t - 1) & 1) << 17) + hread_off;
            const unsigned int tgt = (unsigned int)t;
            unsigned long long hw[64];
            for (;;) {
                // 64 independent 8B coherent loads in flight together
#pragma unroll
                for (int kk = 0; kk < 16; ++kk) {
                    const unsigned long long* q =
                        (const unsigned long long*)(hp + (kk << 13));
#pragma unroll
                    for (int j = 0; j < 4; ++j)
                        hw[kk * 4 + j] = __hip_atomic_load(q + j, __ATOMIC_RELAXED,
                                                           __HIP_MEMORY_SCOPE_AGENT);
                }
                // validate: low 16 bits of each 8B's low word carry the tag;
                // the 8B store was atomic, so one tag validates all 4 bf16
                unsigned int m = 0;
#pragma unroll
                for (int i = 0; i < 64; ++i)
                    m |= ((unsigned int)hw[i] ^ tgt) & 0xffffu;
                if (__all(m == 0)) break;
                if (--budget < 0) break;   // safety valve
            }
            // repack top halves -> bf16 A-fragments and consume
#pragma unroll
            for (int kk = 0; kk < 16; ++kk) {
                unsigned int w0 = (unsigned int)(hw[4 * kk + 0]);
                unsigned int w1 = (unsigned int)(hw[4 * kk + 0] >> 32);
                unsigned int w2 = (unsigned int)(hw[4 * kk + 1]);
                unsigned int w3 = (unsigned int)(hw[4 * kk + 1] >> 32);
                unsigned int w4 = (unsigned int)(hw[4 * kk + 2]);
                unsigned int w5 = (unsigned int)(hw[4 * kk + 2] >> 32);
                unsigned int w6 = (unsigned int)(hw[4 * kk + 3]);
                unsigned int w7 = (unsigned int)(hw[4 * kk + 3] >> 32);
                uint4 u;
                u.x = (w0 >> 16) | (w1 & 0xffff0000u);
                u.y = (w2 >> 16) | (w3 & 0xffff0000u);
                u.z = (w4 >> 16) | (w5 & 0xffff0000u);
                u.w = (w6 >> 16) | (w7 & 0xffff0000u);
                bf16x8 a  = __builtin_bit_cast(bf16x8, u);
                bf16x8 b0 = __builtin_bit_cast(bf16x8, sB[1][0][kk][lane]);
                bf16x8 b1 = __builtin_bit_cast(bf16x8, sB[1][1][kk][lane]);
                acc0 = __builtin_amdgcn_mfma_f32_16x16x32_bf16(a, b0, acc0, 0, 0, 0);
                acc1 = __builtin_amdgcn_mfma_f32_16x16x32_bf16(a, b1, acc1, 0, 0, 0);
            }
        }

        // ---- gates + state update ----
        // C-layout: col = lane&15, row = quad*4 + reg.
        // acc0 col c=l15      : gate i (l15<8) / f (l15>=8), h-col = hc0 + (l15&7)
        // acc1 col c=l15+16   : gate g (l15<8) / o (l15>=8)
        float gi[4], gf[4], gg[4], go[4];
#pragma unroll
        for (int r = 0; r < 4; ++r) {
            float a0 = acc0[r] + bias0;
            float a1 = acc1[r] + bias1;
            float p0 = __shfl_xor(a0, 8, 64);
            float p1 = __shfl_xor(a1, 8, 64);
            gi[r] = a0; gg[r] = a1; gf[r] = p0; go[r] = p1;
        }
        const unsigned int tagv = (unsigned int)(t + 1);
        if (l15 < 8) {
#pragma unroll
            for (int r = 0; r < 4; ++r) {
                float iv = sigmoidf_(gi[r]);
                float fv = sigmoidf_(gf[r]);
                float gv = tanhf_(gg[r]);
                float ov = sigmoidf_(go[r]);
                cst[r] = fv * cst[r] + iv * gv;
                float hv = ov * tanhf_(cst[r]);
                // transpose through per-wave LDS patches (same-wave write->read)
                sHt[w][(quad << 2) + r][l15] =
                    ((unsigned int)f2bf(hv) << 16) | tagv;   // tag rides with data
                sHf[w][(quad << 2) + r][l15] = hv;
            }
        }
        asm volatile("s_waitcnt lgkmcnt(0)" ::: "memory");
        // 32 lanes publish this wave's 16 rows x 32B: fire-and-forget tagged
        // 8B atomics — NO vmcnt ack, NO flag (tag-in-data makes them valid)
        if (lane < 32) {
            int row  = lane >> 1;       // row within wave's M-tile
            int half = lane & 1;        // which 16 B of the 32 B row-slice
            uint4 v = *(const uint4*)&sHt[w][row][half << 2];
            char* dst = hb_base + ((t & 1) << 17) + (blk << 11)
                        + (((w << 4) + row) << 5) + (half << 4);
            store_cg16(dst, v);
        }

        // ---- fp32 output stores: coalesced, OFF the critical chain ----
        if (lane < 32) {
            int row  = lane & 15;        // row within wave's M-tile
            int half = lane >> 4;        // which 16 B of the 32 B row-slice
            uint4 v = *(const uint4*)&sHf[w][row][half << 2];
            float* op = out + (size_t)t * (BATCH * HID)
                        + (size_t)((w << 4) + row) * HID + hc0 + (half << 2);
            *(uint4*)op = v;
        }
    }

    // signal burners: this real block is done
    if (tid == 0) {
        (void)__hip_atomic_fetch_add(done, 1u, __ATOMIC_RELAXED,
                                     __HIP_MEMORY_SCOPE_AGENT);
    }
}

extern "C" void kernel_launch(void* const* d_in, const int* in_sizes, int n_in,
                              void* d_out, int out_size, void* d_ws, size_t ws_size,
                              hipStream_t stream) {
    const float* x    = (const float*)d_in[0];
    const float* W_ih = (const float*)d_in[1];
    const float* W_hh = (const float*)d_in[2];
    const float* b_ih = (const float*)d_in[3];
    const float* b_hh = (const float*)d_in[4];
    float* out = (float*)d_out;

    // hbuf: [2][64 producers][64 rows][8 cols] u32 tagged = 256 KB
    unsigned int* hbuf = (unsigned int*)d_ws;
    unsigned int* done = (unsigned int*)((char*)d_ws + HBUF_BYTES);
    // zero tags + done counter each call (tag 0 never matches tgt>=1; also
    // guards against harness poison 0xAA pattern)
    (void)hipMemsetAsync(d_ws, 0, HBUF_BYTES + 64, stream);

    hipLaunchKernelGGL(lstm_fused, dim3(NB_TOT), dim3(256), 0, stream,
                       x, W_ih, W_hh, b_ih, b_hh, out, hbuf, done);
}